// Round 1
// baseline (22975.026 us; speedup 1.0000x reference)
//
#include <hip/hip_runtime.h>

#define T_STEPS 2048
#define BATCH   64
#define INPUT   512
#define HID     512
#define GM      16      // batch elems per group (MFMA M)
#define NSLICE  32      // blocks per group, each owns 16 hidden cols
#define NKT     32      // K tiles of 32 (K = 512 x-part + 512 h-part)

typedef __bf16 bf16x8 __attribute__((ext_vector_type(8)));
typedef float  f32x4  __attribute__((ext_vector_type(4)));

union U4 { uint4 u; bf16x8 v; };

__device__ __forceinline__ float sigmoid_f(float x) { return 1.0f / (1.0f + __expf(-x)); }

__global__ void init_flags_kernel(unsigned int* flags) {
    if (threadIdx.x < 4 * NSLICE) flags[threadIdx.x] = 0u;
}

__global__ void __launch_bounds__(256, 1)
lstm_persistent(const float* __restrict__ inp, const float* __restrict__ h0,
                const float* __restrict__ c0, const float* __restrict__ W_ih,
                const float* __restrict__ W_hh, const float* __restrict__ b_ih,
                const float* __restrict__ b_hh, float* __restrict__ out,
                unsigned int* flags, unsigned int* h_ex)
{
    __shared__ U4 ldsA[NKT * 64];         // 32 KB, fragment-ordered A = [x_t | h_t] bf16
    __shared__ float ldsG[4 * 256];       // 4 KB, gates i,f,g,o (fp32, bias added)
    __shared__ unsigned short ldsH[256];  // new h as bf16 bit patterns

    const int tid  = threadIdx.x;
    const int wv   = tid >> 6;    // wave = gate index (i,f,g,o)
    const int lane = tid & 63;
    const int fn   = lane & 15;   // fragment 16-index
    const int fq   = lane >> 4;   // fragment quad
    const int bg   = blockIdx.x & 3;   // batch group
    const int sl   = blockIdx.x >> 2;  // hidden slice [sl*16, sl*16+16)

    // ---- one-time: weight fragments into registers (16 gate cols x K=1024, bf16)
    // wave wv's gate col for this lane: global col = wv*512 + sl*16 + fn
    const int col = wv * HID + sl * 16 + fn;
    bf16x8 wfrag[NKT];
#pragma unroll
    for (int kt = 0; kt < NKT; ++kt) {
        const float* src = (kt < 16)
            ? (W_ih + (size_t)col * INPUT + kt * 32 + fq * 8)
            : (W_hh + (size_t)col * HID + (kt - 16) * 32 + fq * 8);
        bf16x8 v;
#pragma unroll
        for (int j = 0; j < 8; ++j) v[j] = (__bf16)src[j];
        wfrag[kt] = v;
    }
    const float bias = b_ih[col] + b_hh[col];

    // ---- private cell state: thread owns (batch eb, hidden ej) of this block's 16x16
    const int eb = tid >> 4;
    const int ej = tid & 15;
    float c = c0[(size_t)(bg * GM + eb) * HID + sl * 16 + ej];

    const size_t outHT = (size_t)T_STEPS * BATCH * HID;
    const size_t outCT = outHT + (size_t)BATCH * HID;
    const int HEXH = BATCH * HID / 2;   // u32 elems per h buffer

    for (int t = 0; t < T_STEPS; ++t) {
        // ---- stage x half (K tiles 0..15): global fp32 -> bf16 fragment order
#pragma unroll
        for (int r = 0; r < 4; ++r) {
            const int p  = tid + 256 * r;        // 1024 (ktile,lane) pairs
            const int kt = p >> 6;
            const int ln = p & 63;
            const int m  = ln & 15;
            const int k0 = kt * 32 + ((ln >> 4) * 8);
            const float* src = inp + ((size_t)t * BATCH + bg * GM + m) * INPUT + k0;
            const float4 x0 = *(const float4*)src;
            const float4 x1 = *(const float4*)(src + 4);
            U4 u;
            u.v[0] = (__bf16)x0.x; u.v[1] = (__bf16)x0.y;
            u.v[2] = (__bf16)x0.z; u.v[3] = (__bf16)x0.w;
            u.v[4] = (__bf16)x1.x; u.v[5] = (__bf16)x1.y;
            u.v[6] = (__bf16)x1.z; u.v[7] = (__bf16)x1.w;
            ldsA[kt * 64 + ln] = u;
        }

        // ---- wait for all 32 slices of previous step's h
        if (t > 0 && tid < NSLICE) {
            while ((int)__hip_atomic_load(&flags[bg * NSLICE + tid], __ATOMIC_ACQUIRE,
                                          __HIP_MEMORY_SCOPE_AGENT) < t)
                __builtin_amdgcn_s_sleep(1);
        }
        __syncthreads();

        // ---- stage h half (K tiles 16..31)
        if (t == 0) {
#pragma unroll
            for (int r = 0; r < 4; ++r) {
                const int p   = tid + 256 * r;
                const int kth = p >> 6;
                const int ln  = p & 63;
                const int m   = ln & 15;
                const int k0  = kth * 32 + ((ln >> 4) * 8);
                const float* src = h0 + (size_t)(bg * GM + m) * HID + k0;
                const float4 x0 = *(const float4*)src;
                const float4 x1 = *(const float4*)(src + 4);
                U4 u;
                u.v[0] = (__bf16)x0.x; u.v[1] = (__bf16)x0.y;
                u.v[2] = (__bf16)x0.z; u.v[3] = (__bf16)x0.w;
                u.v[4] = (__bf16)x1.x; u.v[5] = (__bf16)x1.y;
                u.v[6] = (__bf16)x1.z; u.v[7] = (__bf16)x1.w;
                ldsA[(16 + kth) * 64 + ln] = u;
            }
        } else {
            unsigned int* hb = h_ex + ((t & 1) ^ 1) * HEXH;
#pragma unroll
            for (int r = 0; r < 4; ++r) {
                const int p   = tid + 256 * r;
                const int kth = p >> 6;
                const int ln  = p & 63;
                const int m   = ln & 15;
                const int k0  = kth * 32 + ((ln >> 4) * 8);
                const unsigned int base = (((unsigned)(bg * GM + m)) * HID + k0) >> 1;
                U4 u;
                u.u.x = __hip_atomic_load(hb + base + 0, __ATOMIC_RELAXED, __HIP_MEMORY_SCOPE_AGENT);
                u.u.y = __hip_atomic_load(hb + base + 1, __ATOMIC_RELAXED, __HIP_MEMORY_SCOPE_AGENT);
                u.u.z = __hip_atomic_load(hb + base + 2, __ATOMIC_RELAXED, __HIP_MEMORY_SCOPE_AGENT);
                u.u.w = __hip_atomic_load(hb + base + 3, __ATOMIC_RELAXED, __HIP_MEMORY_SCOPE_AGENT);
                ldsA[(16 + kth) * 64 + ln] = u;
            }
        }
        __syncthreads();

        // ---- MFMA K loop: D[m=batch][n=gatecol] += A[m][k] * W[n][k]
        f32x4 acc = {0.f, 0.f, 0.f, 0.f};
#pragma unroll
        for (int kt = 0; kt < NKT; ++kt) {
            acc = __builtin_amdgcn_mfma_f32_16x16x32_bf16(ldsA[kt * 64 + lane].v,
                                                          wfrag[kt], acc, 0, 0, 0);
        }

        // ---- gates to LDS (C/D layout: row m = fq*4+r, col n = fn)
#pragma unroll
        for (int r = 0; r < 4; ++r) {
            ldsG[wv * 256 + (fq * 4 + r) * 16 + fn] = acc[r] + bias;
        }
        __syncthreads();

        // ---- LSTM cell update (thread owns (eb, ej); tid == eb*16+ej)
        {
            const float ig = sigmoid_f(ldsG[0 * 256 + tid]);
            const float fg = sigmoid_f(ldsG[1 * 256 + tid]);
            const float gg = tanhf(ldsG[2 * 256 + tid]);
            const float og = sigmoid_f(ldsG[3 * 256 + tid]);
            c = fg * c + ig * gg;
            const float h = og * tanhf(c);
            const size_t oidx = ((size_t)t * BATCH + bg * GM + eb) * HID + sl * 16 + ej;
            out[oidx] = h;
            if (t == T_STEPS - 1) {
                out[outHT + (size_t)(bg * GM + eb) * HID + sl * 16 + ej] = h;
                out[outCT + (size_t)(bg * GM + eb) * HID + sl * 16 + ej] = c;
            }
            union { __bf16 b; unsigned short u; } cv;
            cv.b = (__bf16)h;
            ldsH[tid] = cv.u;
        }
        __syncthreads();

        // ---- publish h slice (bf16 pairs) to the exchange buffer
        if (tid < 128) {
            const int b2 = tid >> 3;
            const int jp = (tid & 7) * 2;
            const unsigned int v = (unsigned int)ldsH[b2 * 16 + jp] |
                                   ((unsigned int)ldsH[b2 * 16 + jp + 1] << 16);
            unsigned int* hb = h_ex + (t & 1) * HEXH;
            const unsigned int idx = (((unsigned)(bg * GM + b2)) * HID + sl * 16 + jp) >> 1;
            __hip_atomic_store(hb + idx, v, __ATOMIC_RELAXED, __HIP_MEMORY_SCOPE_AGENT);
        }
        __syncthreads();   // drains all threads' stores (vmcnt(0) before barrier)
        if (tid == 0) {
            __threadfence();
            __hip_atomic_store(&flags[bg * NSLICE + sl], (unsigned)(t + 1),
                               __ATOMIC_RELEASE, __HIP_MEMORY_SCOPE_AGENT);
        }
    }
}

extern "C" void kernel_launch(void* const* d_in, const int* in_sizes, int n_in,
                              void* d_out, int out_size, void* d_ws, size_t ws_size,
                              hipStream_t stream) {
    (void)in_sizes; (void)n_in; (void)out_size; (void)ws_size;
    const float* inp  = (const float*)d_in[0];
    const float* h0   = (const float*)d_in[1];
    const float* c0   = (const float*)d_in[2];
    const float* W_ih = (const float*)d_in[3];
    const float* W_hh = (const float*)d_in[4];
    const float* b_ih = (const float*)d_in[5];
    const float* b_hh = (const float*)d_in[6];
    float* out = (float*)d_out;

    unsigned int* flags = (unsigned int*)d_ws;                      // 128 u32
    unsigned int* h_ex  = (unsigned int*)((char*)d_ws + 4096);      // 2 x 64 x 512 bf16 = 128 KB

    hipLaunchKernelGGL(init_flags_kernel, dim3(1), dim3(128), 0, stream, flags);
    hipLaunchKernelGGL(lstm_persistent, dim3(128), dim3(256), 0, stream,
                       inp, h0, c0, W_ih, W_hh, b_ih, b_hh, out, flags, h_ex);
}

// Round 2
// 8257.795 us; speedup vs baseline: 2.7822x; 2.7822x over previous
//
#include <hip/hip_runtime.h>

#define T_STEPS 2048
#define BATCH   64
#define INPUT   512
#define HID     512
#define GM      16      // batch elems per group (MFMA M)
#define NSLICE  32      // blocks per group, each owns 16 hidden cols
#define NKT     32      // K tiles of 32 (K = 512 x-part + 512 h-part)

typedef __bf16 bf16x8 __attribute__((ext_vector_type(8)));
typedef float  f32x4  __attribute__((ext_vector_type(4)));

union U4 { uint4 u; bf16x8 v; };

__device__ __forceinline__ float sigmoid_f(float x) { return 1.0f / (1.0f + __expf(-x)); }
// tanh via __expf; t in (0,1], no inf/NaN path. Accuracy ~1e-6 rel, fine vs 3.5e-2 threshold.
__device__ __forceinline__ float tanh_f(float x) {
    float ax = fabsf(x);
    float t  = __expf(-2.0f * ax);
    float r  = (1.0f - t) / (1.0f + t);
    return copysignf(r, x);
}

__global__ void init_flags_kernel(unsigned int* ctr) {
    if (threadIdx.x < 128) ctr[threadIdx.x] = 0u;
}

__global__ void __launch_bounds__(256, 1)
lstm_persistent(const float* __restrict__ inp, const float* __restrict__ h0,
                const float* __restrict__ c0, const float* __restrict__ W_ih,
                const float* __restrict__ W_hh, const float* __restrict__ b_ih,
                const float* __restrict__ b_hh, float* __restrict__ out,
                unsigned int* ctr, unsigned int* h_ex)
{
    __shared__ U4 ldsA[NKT * 64];         // 32 KB, fragment-ordered A = [x_t | h_t] bf16
    __shared__ float ldsG[4 * 256];       // 4 KB, gates i,f,g,o (fp32)

    const int tid  = threadIdx.x;
    const int wv   = tid >> 6;    // wave = gate index (i,f,g,o)
    const int lane = tid & 63;
    const int fn   = lane & 15;   // fragment 16-index
    const int fq   = lane >> 4;   // fragment quad
    const int bg   = blockIdx.x & 3;   // batch group
    const int sl   = blockIdx.x >> 2;  // hidden slice [sl*16, sl*16+16)

    // ---- one-time: weight fragments into registers (16 gate cols x K=1024, bf16)
    const int col = wv * HID + sl * 16 + fn;
    bf16x8 wfrag[NKT];
#pragma unroll
    for (int kt = 0; kt < NKT; ++kt) {
        const float* src = (kt < 16)
            ? (W_ih + (size_t)col * INPUT + kt * 32 + fq * 8)
            : (W_hh + (size_t)col * HID + (kt - 16) * 32 + fq * 8);
        bf16x8 v;
#pragma unroll
        for (int j = 0; j < 8; ++j) v[j] = (__bf16)src[j];
        wfrag[kt] = v;
    }
    const float bias = b_ih[col] + b_hh[col];

    // ---- private cell state: thread owns (batch eb, hidden ej) of this block's 16x16
    const int eb = tid >> 4;
    const int ej = tid & 15;
    float c = c0[(size_t)(bg * GM + eb) * HID + sl * 16 + ej];

    const size_t outHT = (size_t)T_STEPS * BATCH * HID;
    const size_t outCT = outHT + (size_t)BATCH * HID;
    const int HEXH = BATCH * HID / 2;   // u32 elems per h buffer

    unsigned int* my_ctr = ctr + bg;

    for (int t = 0; t < T_STEPS; ++t) {
        // ---- stage x half (K tiles 0..15): global fp32 -> bf16 fragment order
#pragma unroll
        for (int r = 0; r < 4; ++r) {
            const int p  = tid + 256 * r;        // 1024 (ktile,lane) pairs
            const int kt = p >> 6;
            const int ln = p & 63;
            const int m  = ln & 15;
            const int k0 = kt * 32 + ((ln >> 4) * 8);
            const float* src = inp + ((size_t)t * BATCH + bg * GM + m) * INPUT + k0;
            const float4 x0 = *(const float4*)src;
            const float4 x1 = *(const float4*)(src + 4);
            U4 u;
            u.v[0] = (__bf16)x0.x; u.v[1] = (__bf16)x0.y;
            u.v[2] = (__bf16)x0.z; u.v[3] = (__bf16)x0.w;
            u.v[4] = (__bf16)x1.x; u.v[5] = (__bf16)x1.y;
            u.v[6] = (__bf16)x1.z; u.v[7] = (__bf16)x1.w;
            ldsA[kt * 64 + ln] = u;
        }
        __syncthreads();

        // ---- x-half MFMAs (independent of h, overlaps the wait below)
        f32x4 acc = {0.f, 0.f, 0.f, 0.f};
#pragma unroll
        for (int kt = 0; kt < 16; ++kt) {
            acc = __builtin_amdgcn_mfma_f32_16x16x32_bf16(ldsA[kt * 64 + lane].v,
                                                          wfrag[kt], acc, 0, 0, 0);
        }

        // ---- wait for all 32 slices of previous step's h (single poller, bypass loads)
        if (t > 0 && tid == 0) {
            const unsigned int tgt = 32u * (unsigned int)t;
            unsigned int v;
            do {
                asm volatile("global_load_dword %0, %1, off sc0 sc1\n\ts_waitcnt vmcnt(0)"
                             : "=v"(v) : "v"(my_ctr) : "memory");
            } while (v < tgt);
        }
        __syncthreads();

        // ---- stage h half (K tiles 16..31)
        if (t == 0) {
#pragma unroll
            for (int r = 0; r < 4; ++r) {
                const int p   = tid + 256 * r;
                const int kth = p >> 6;
                const int ln  = p & 63;
                const int m   = ln & 15;
                const int k0  = kth * 32 + ((ln >> 4) * 8);
                const float* src = h0 + (size_t)(bg * GM + m) * HID + k0;
                const float4 x0 = *(const float4*)src;
                const float4 x1 = *(const float4*)(src + 4);
                U4 u;
                u.v[0] = (__bf16)x0.x; u.v[1] = (__bf16)x0.y;
                u.v[2] = (__bf16)x0.z; u.v[3] = (__bf16)x0.w;
                u.v[4] = (__bf16)x1.x; u.v[5] = (__bf16)x1.y;
                u.v[6] = (__bf16)x1.z; u.v[7] = (__bf16)x1.w;
                ldsA[(16 + kth) * 64 + ln] = u;
            }
        } else {
            const unsigned int* hb = h_ex + ((t & 1) ^ 1) * HEXH;
            uint4 q0, q1, q2, q3;
            const unsigned int* pp[4];
#pragma unroll
            for (int r = 0; r < 4; ++r) {
                const int p   = tid + 256 * r;
                const int kth = p >> 6;
                const int ln  = p & 63;
                const int m   = ln & 15;
                const int k0  = kth * 32 + ((ln >> 4) * 8);
                pp[r] = hb + (((unsigned int)(bg * GM + m) * HID + k0) >> 1);
            }
            // Batched bypass loads (sc0 sc1 -> read at coherence point), one drain.
            asm volatile("global_load_dwordx4 %0, %1, off sc0 sc1" : "=v"(q0) : "v"(pp[0]) : "memory");
            asm volatile("global_load_dwordx4 %0, %1, off sc0 sc1" : "=v"(q1) : "v"(pp[1]) : "memory");
            asm volatile("global_load_dwordx4 %0, %1, off sc0 sc1" : "=v"(q2) : "v"(pp[2]) : "memory");
            asm volatile("global_load_dwordx4 %0, %1, off sc0 sc1" : "=v"(q3) : "v"(pp[3]) : "memory");
            asm volatile("s_waitcnt vmcnt(0)" ::: "memory");
#pragma unroll
            for (int r = 0; r < 4; ++r) {
                const int p   = tid + 256 * r;
                const int kth = p >> 6;
                const int ln  = p & 63;
                U4 u;
                u.u = (r == 0) ? q0 : (r == 1) ? q1 : (r == 2) ? q2 : q3;
                ldsA[(16 + kth) * 64 + ln] = u;
            }
        }
        __syncthreads();

        // ---- h-half MFMAs
#pragma unroll
        for (int kt = 16; kt < NKT; ++kt) {
            acc = __builtin_amdgcn_mfma_f32_16x16x32_bf16(ldsA[kt * 64 + lane].v,
                                                          wfrag[kt], acc, 0, 0, 0);
        }

        // ---- gates to LDS (C/D layout: row m = fq*4+r, col n = fn)
#pragma unroll
        for (int r = 0; r < 4; ++r) {
            ldsG[wv * 256 + (fq * 4 + r) * 16 + fn] = acc[r] + bias;
        }
        __syncthreads();

        // ---- LSTM cell update (thread owns (eb, ej); tid == eb*16+ej)
        {
            const float ig = sigmoid_f(ldsG[0 * 256 + tid]);
            const float fg = sigmoid_f(ldsG[1 * 256 + tid]);
            const float gg = tanh_f(ldsG[2 * 256 + tid]);
            const float og = sigmoid_f(ldsG[3 * 256 + tid]);
            c = fg * c + ig * gg;
            const float h = og * tanh_f(c);
            const size_t oidx = ((size_t)t * BATCH + bg * GM + eb) * HID + sl * 16 + ej;
            out[oidx] = h;
            if (t == T_STEPS - 1) {
                out[outHT + (size_t)(bg * GM + eb) * HID + sl * 16 + ej] = h;
                out[outCT + (size_t)(bg * GM + eb) * HID + sl * 16 + ej] = c;
            }
            // pack bf16 pair with the lane^1 partner (same wave: ej and ej^1 share eb)
            union { __bf16 b; unsigned short u; } cv;
            cv.b = (__bf16)h;
            const unsigned int mine    = cv.u;
            const unsigned int partner = (unsigned int)(unsigned short)
                __shfl_xor((int)mine, 1, 64);
            if ((ej & 1) == 0) {
                const unsigned int v = mine | (partner << 16);
                unsigned int* dst = h_ex + (t & 1) * HEXH +
                    (((unsigned int)(bg * GM + eb) * HID + sl * 16 + ej) >> 1);
                // bypass store + personal drain: acked at coherence point before barrier
                asm volatile("global_store_dword %0, %1, off sc0 sc1\n\ts_waitcnt vmcnt(0)"
                             :: "v"(dst), "v"(v) : "memory");
            }
        }
        __syncthreads();   // all 128 publish stores acked at MALL

        if (tid == 0) {
            atomicAdd(my_ctr, 1u);   // device-scope RMW (m20): coherent cross-XCD
        }
    }
}

extern "C" void kernel_launch(void* const* d_in, const int* in_sizes, int n_in,
                              void* d_out, int out_size, void* d_ws, size_t ws_size,
                              hipStream_t stream) {
    (void)in_sizes; (void)n_in; (void)out_size; (void)ws_size;
    const float* inp  = (const float*)d_in[0];
    const float* h0   = (const float*)d_in[1];
    const float* c0   = (const float*)d_in[2];
    const float* W_ih = (const float*)d_in[3];
    const float* W_hh = (const float*)d_in[4];
    const float* b_ih = (const float*)d_in[5];
    const float* b_hh = (const float*)d_in[6];
    float* out = (float*)d_out;

    unsigned int* ctr  = (unsigned int*)d_ws;                      // 4 u32 used
    unsigned int* h_ex = (unsigned int*)((char*)d_ws + 4096);      // 2 x 64 x 512 bf16 = 128 KB

    hipLaunchKernelGGL(init_flags_kernel, dim3(1), dim3(128), 0, stream, ctr);
    hipLaunchKernelGGL(lstm_persistent, dim3(128), dim3(256), 0, stream,
                       inp, h0, c0, W_ih, W_hh, b_ih, b_hh, out, ctr, h_ex);
}